// Round 4
// baseline (465.640 us; speedup 1.0000x reference)
//
#include <hip/hip_runtime.h>

// irreps Linear: out[n, off_l + w*d + i] = 0.125 * sum_u x[n, off_l + u*d + i] * Wl[u][w]
// N=262144 rows of 576 = [64x(d=1) | 64x(d=3) | 64x(d=5)].
// BW floor: 1.21 GB @ ~6.3 TB/s => ~190 us. R3 = 248 us (77%).
// R4: persistent double-buffered pipeline (T14). 1024 WGs x 16 tiles each;
// next tile's global loads are issued into REGISTERS before compute, so HBM
// read latency hides under compute+scatter+copyout. LDS unchanged (36 KB,
// stage region aliases out-tile region) -> 4 blocks/CU. Scatter gets an XOR
// bank-spread (involution, undone in copy-out).

typedef _Float16 half4  __attribute__((ext_vector_type(4)));
typedef float    f32x4  __attribute__((ext_vector_type(4)));

#define RPB      16                 // rows per tile
#define NROWS    262144
#define ROWF     576                // floats per row
#define NTILES   (NROWS / RPB)      // 16384
#define WGS      1024               // persistent workgroups (4 per CU)
#define TPW      (NTILES / WGS)     // 16 tiles per WG
#define OUTBYTES (RPB * ROWF * 4)   // 36864 = out tile f32 (aliases x-stage 18432)
#define LDS_BYTES OUTBYTES

// ---- load one l-segment's float4s into registers (linear-ish, coalesced)
template<int OFF, int F4PR, int NIT>
__device__ __forceinline__ void seg_load(const float* __restrict__ xrow0, int tid, f32x4* pf) {
#pragma unroll
  for (int it = 0; it < NIT; ++it) {
    int t = tid + it * 256;
    int row = t / F4PR;                 // const divisor -> magic mul
    int f4  = t - row * F4PR;
    pf[it] = *(const f32x4*)(xrow0 + (long long)row * ROWF + OFF + f4 * 4);
  }
}

// ---- convert staged regs -> f16 LDS; LDS rows = (n_local*D + i), cols = u.
// XOR swizzle (row&7)<<4 breaks the 128B-stride same-bank pattern.
template<int D, int SEGROW, int F4PR, int NIT>
__device__ __forceinline__ void seg_write(unsigned char* lds, int tid, const f32x4* pf) {
#pragma unroll
  for (int it = 0; it < NIT; ++it) {
    int t = tid + it * 256;
    int row = t / F4PR;
    int f4  = t - row * F4PR;
    f32x4 v = pf[it];
    int idx = f4 * 4;                   // element index within segment (= u*D + i)
    if (D == 1) {
      int lrow = SEGROW + row;
      int b = (lrow * 128 + idx * 2) ^ ((lrow & 7) << 4);
      half4 h = { (_Float16)v[0], (_Float16)v[1], (_Float16)v[2], (_Float16)v[3] };
      *(half4*)(lds + b) = h;           // 4 consecutive u: one 8B write
    } else {
#pragma unroll
      for (int j = 0; j < 4; ++j) {
        int u = (idx + j) / D;          // const divisor
        int i = (idx + j) - u * D;
        int lrow = SEGROW + row * D + i;
        int b = (lrow * 128 + u * 2) ^ ((lrow & 7) << 4);
        *(_Float16*)(lds + b) = (_Float16)v[j];
      }
    }
  }
}

// B-fragments for this wave's wt: bf[s][j] = W[u = s*16 + 4*laneq + j][w = wt*16 + lane15]
__device__ __forceinline__ void load_bfrag(const float* __restrict__ W, int wt,
                                           int lane15, int laneq, half4 bf[4]) {
  int w = wt * 16 + lane15;
#pragma unroll
  for (int s = 0; s < 4; ++s) {
    int u0 = s * 16 + laneq * 4;
#pragma unroll
    for (int j = 0; j < 4; ++j)
      bf[s][j] = (_Float16)W[(u0 + j) * 64 + w];   // 16-lane groups read 64B contig
  }
}

// MFMA all m-tiles of one l-segment for this wave's w-tile
template<int SEGROW, int MT>
__device__ __forceinline__ void compute_seg(const unsigned char* lds, int lane15, int laneq,
                                            const half4 bf[4], f32x4 acc[MT]) {
  const int coff = laneq * 8;           // k-chunk byte offset within a row
#pragma unroll
  for (int mt = 0; mt < MT; ++mt) {
    int arow  = SEGROW + mt * 16 + lane15;   // A: m = lane%16, k = s*16 + 4*laneq + j
    int abase = arow * 128;
    int aswz  = (arow & 7) << 4;
    acc[mt] = (f32x4){0.f, 0.f, 0.f, 0.f};
#pragma unroll
    for (int s = 0; s < 4; ++s) {
      half4 a = *(const half4*)(lds + abase + ((s * 32 + coff) ^ aswz));
      acc[mt] = __builtin_amdgcn_mfma_f32_16x16x16f16(a, bf[s], acc[mt], 0, 0, 0);
    }
  }
}

// scatter acc fragments into the f32 out tile in LDS ([RPB][576] row-major,
// byte addr XOR'd with ((n>>2)&3)<<5 for bank spread; undone in copy-out)
template<int D, int OFF, int MT>
__device__ __forceinline__ void scatter_seg(unsigned char* lds, int wt, int lane15, int laneq,
                                            const f32x4 acc[MT]) {
  const int w = wt * 16 + lane15;
#pragma unroll
  for (int mt = 0; mt < MT; ++mt) {
#pragma unroll
    for (int j = 0; j < 4; ++j) {
      int r = mt * 16 + laneq * 4 + j;  // D-frag: col = lane&15, row = 4*laneq + j
      int n = r / D;                    // const divisor
      int i = r - n * D;
      int b = (n * (ROWF * 4) + (OFF + w * D + i) * 4) ^ (((n >> 2) & 3) << 5);
      *(float*)(lds + b) = 0.125f * acc[mt][j];
    }
  }
}

__global__ __launch_bounds__(256, 4) void linear_irreps(
    const float* __restrict__ x,
    const float* __restrict__ w0, const float* __restrict__ w1, const float* __restrict__ w2,
    float* __restrict__ out) {
  __shared__ __align__(16) unsigned char lds[LDS_BYTES];
  const int tid = threadIdx.x;
  const int lane = tid & 63, wave = tid >> 6;
  const int lane15 = lane & 15, laneq = lane >> 4;
  const int wt = wave;                  // 4 waves <-> 4 w-tiles (w = wt*16 .. +15)
  const int wg = blockIdx.x;

  // weights -> registers (L2-hot after first wave of blocks)
  half4 bf0[4], bf1[4], bf2[4];
  load_bfrag(w0, wt, lane15, laneq, bf0);
  load_bfrag(w1, wt, lane15, laneq, bf1);
  load_bfrag(w2, wt, lane15, laneq, bf2);

  f32x4 pf[9];                          // prefetch regs: [0]=seg1, [1..3]=seg3, [4..8]=seg5

  // prologue: issue tile-0 loads
  {
    const float* xs = x + (long long)wg * (RPB * ROWF);
    seg_load<  0, 16, 1>(xs, tid, pf + 0);
    seg_load< 64, 48, 3>(xs, tid, pf + 1);
    seg_load<256, 80, 5>(xs, tid, pf + 4);
  }

  for (int it = 0; it < TPW; ++it) {
    const long long tile = wg + (long long)it * WGS;

    // regs -> f16 LDS (compiler inserts per-reg vmcnt waits)
    seg_write<1,   0, 16, 1>(lds, tid, pf + 0);
    seg_write<3,  16, 48, 3>(lds, tid, pf + 1);
    seg_write<5,  64, 80, 5>(lds, tid, pf + 4);
    __syncthreads();

    // issue NEXT tile's loads now: latency hides under compute+scatter+copy
    if (it + 1 < TPW) {
      const float* xs = x + (tile + WGS) * (RPB * ROWF);
      seg_load<  0, 16, 1>(xs, tid, pf + 0);
      seg_load< 64, 48, 3>(xs, tid, pf + 1);
      seg_load<256, 80, 5>(xs, tid, pf + 4);
    }

    // MFMA into registers (36 f32 accs/thread)
    f32x4 acc1[1], acc3[3], acc5[5];
    compute_seg<  0, 1>(lds, lane15, laneq, bf0, acc1);
    compute_seg< 16, 3>(lds, lane15, laneq, bf1, acc3);
    compute_seg< 64, 5>(lds, lane15, laneq, bf2, acc5);
    __syncthreads();                    // x-stage region dead before OUT overwrite

    // scatter f32 results into LDS out tile
    scatter_seg<1,   0, 1>(lds, wt, lane15, laneq, acc1);
    scatter_seg<3,  64, 3>(lds, wt, lane15, laneq, acc3);
    scatter_seg<5, 256, 5>(lds, wt, lane15, laneq, acc5);
    __syncthreads();

    // fully-coalesced copy out: 9 x dwordx4 per thread (un-XOR the spread)
    float* dst = out + tile * (RPB * ROWF);
#pragma unroll
    for (int k = 0; k < OUTBYTES / 4096; ++k) {    // 9
      int q = tid + k * 256;
      int n = q / 144;                  // 144 float4s per 576-f row
      f32x4 v = *(const f32x4*)(lds + ((q * 16) ^ (((n >> 2) & 3) << 5)));
      *(f32x4*)(dst + q * 4) = v;
    }
    __syncthreads();                    // OUT dead before next iteration's seg_write
  }
}

extern "C" void kernel_launch(void* const* d_in, const int* in_sizes, int n_in,
                              void* d_out, int out_size, void* d_ws, size_t ws_size,
                              hipStream_t stream) {
  const float* x  = (const float*)d_in[0];
  const float* w0 = (const float*)d_in[1];
  const float* w1 = (const float*)d_in[2];
  const float* w2 = (const float*)d_in[3];
  float* out = (float*)d_out;
  linear_irreps<<<WGS, 256, 0, stream>>>(x, w0, w1, w2, out);
}

// Round 5
// 260.627 us; speedup vs baseline: 1.7866x; 1.7866x over previous
//
#include <hip/hip_runtime.h>

// irreps Linear: out[n, off_l + w*d + i] = 0.125 * sum_u x[n, off_l + u*d + i] * Wl[u][w]
// N=262144 rows of 576 = [64x(d=1) | 64x(d=3) | 64x(d=5)].
// BW floor: 1.21 GB @ ~6.3 TB/s => ~190 us. R3 (4 blocks/CU) = 248 us.
// R5: occupancy push. LDS cut 36864 -> 18432 by copying the output out in TWO
// 8-row half-tiles (accs stay in regs between phases). With VGPR<=64 this gives
// 8 blocks/CU = 32 waves/CU (hardware max) so the per-block read/compute/write
// phase gaps are covered by 2x more out-of-phase neighbors.
// (R4 lesson: source-level reg-prefetch across barriers gets defeated by the
//  compiler -> scratch traffic; rely on inter-block TLP instead.)

typedef _Float16 half4  __attribute__((ext_vector_type(4)));
typedef float    f32x4  __attribute__((ext_vector_type(4)));

#define RPB      16                 // rows per block
#define NROWS    262144
#define ROWF     576                // floats per row
#define HTROWS   8                  // rows per copy-out half-tile
#define LDS_BYTES (HTROWS * ROWF * 4)  // 18432 = x-stage (144*128) = out half-tile

// ---- stage one l-segment of x into LDS as f16; LDS rows = (n_local*D + i), cols = u.
// XOR swizzle (row&7)<<4 breaks the 128B-stride same-bank pattern.
template<int D, int OFF, int SEGROW, int F4PR>   // F4PR = float4s per 576-f row in this seg
__device__ __forceinline__ void stage_seg(unsigned char* lds, const float* __restrict__ xrow0, int tid) {
#pragma unroll
  for (int it = 0; it < RPB * F4PR / 256; ++it) {  // 1 / 3 / 5 iters, no tail
    int t = tid + it * 256;
    int row = t / F4PR;                 // const divisor -> magic mul
    int f4  = t - row * F4PR;
    f32x4 v = *(const f32x4*)(xrow0 + (long long)row * ROWF + OFF + f4 * 4);
    int idx = f4 * 4;                   // element index within segment (= u*D + i)
    if (D == 1) {
      int lrow = SEGROW + row;
      int b = (lrow * 128 + idx * 2) ^ ((lrow & 7) << 4);
      half4 h = { (_Float16)v[0], (_Float16)v[1], (_Float16)v[2], (_Float16)v[3] };
      *(half4*)(lds + b) = h;           // 4 consecutive u: one 8B write
    } else {
#pragma unroll
      for (int j = 0; j < 4; ++j) {
        int u = (idx + j) / D;          // const divisor
        int i = (idx + j) - u * D;
        int lrow = SEGROW + row * D + i;
        int b = (lrow * 128 + u * 2) ^ ((lrow & 7) << 4);
        *(_Float16*)(lds + b) = (_Float16)v[j];
      }
    }
  }
}

// B-fragments for this wave's wt: bf[s][j] = W[u = s*16 + 4*laneq + j][w = wt*16 + lane15]
__device__ __forceinline__ void load_bfrag(const float* __restrict__ W, int wt,
                                           int lane15, int laneq, half4 bf[4]) {
  int w = wt * 16 + lane15;
#pragma unroll
  for (int s = 0; s < 4; ++s) {
    int u0 = s * 16 + laneq * 4;
#pragma unroll
    for (int j = 0; j < 4; ++j)
      bf[s][j] = (_Float16)W[(u0 + j) * 64 + w];   // 16-lane groups read 64B contig
  }
}

// MFMA all m-tiles of one l-segment for this wave's w-tile
template<int SEGROW, int MT>
__device__ __forceinline__ void compute_seg(const unsigned char* lds, int lane15, int laneq,
                                            const half4 bf[4], f32x4 acc[MT]) {
  const int coff = laneq * 8;           // k-chunk byte offset within a row
#pragma unroll
  for (int mt = 0; mt < MT; ++mt) {
    int arow  = SEGROW + mt * 16 + lane15;   // A: m = lane%16, k = s*16 + 4*laneq + j
    int abase = arow * 128;
    int aswz  = (arow & 7) << 4;
    acc[mt] = (f32x4){0.f, 0.f, 0.f, 0.f};
#pragma unroll
    for (int s = 0; s < 4; ++s) {
      half4 a = *(const half4*)(lds + abase + ((s * 32 + coff) ^ aswz));
      acc[mt] = __builtin_amdgcn_mfma_f32_16x16x16f16(a, bf[s], acc[mt], 0, 0, 0);
    }
  }
}

// scatter this phase's acc fragments into the f32 half-tile in LDS
// (rows n in [PHASE*8, PHASE*8+8), stored at row n - PHASE*8, row-major [8][576])
template<int D, int OFF, int MT, int PHASE>
__device__ __forceinline__ void scatter_seg(unsigned char* lds, int wt, int lane15, int laneq,
                                            const f32x4 acc[MT]) {
  const int w = wt * 16 + lane15;
#pragma unroll
  for (int mt = 0; mt < MT; ++mt) {
#pragma unroll
    for (int j = 0; j < 4; ++j) {
      int r = mt * 16 + laneq * 4 + j;  // D-frag: col = lane&15, row = 4*laneq + j
      int n = r / D;                    // const divisor
      int i = r - n * D;
      bool sel = PHASE ? (n >= HTROWS) : (n < HTROWS);
      if (sel)
        *(float*)(lds + (n - PHASE * HTROWS) * (ROWF * 4) + (OFF + w * D + i) * 4)
            = 0.125f * acc[mt][j];
    }
  }
}

// coalesced copy of one 8x576 f32 half-tile to global (1152 float4s, 256 threads)
__device__ __forceinline__ void copy_half(const unsigned char* lds, float* __restrict__ dst, int tid) {
#pragma unroll
  for (int k = 0; k < 4; ++k) {
    int q = tid + k * 256;
    *(f32x4*)(dst + q * 4) = *(const f32x4*)(lds + q * 16);
  }
  if (tid < 128) {
    int q = tid + 1024;
    *(f32x4*)(dst + q * 4) = *(const f32x4*)(lds + q * 16);
  }
}

__global__ __launch_bounds__(256, 8) void linear_irreps(
    const float* __restrict__ x,
    const float* __restrict__ w0, const float* __restrict__ w1, const float* __restrict__ w2,
    float* __restrict__ out) {
  __shared__ __align__(16) unsigned char lds[LDS_BYTES];
  const int tid = threadIdx.x;
  const int lane = tid & 63, wave = tid >> 6;
  const int lane15 = lane & 15, laneq = lane >> 4;
  const int wt = wave;                  // 4 waves <-> 4 w-tiles (w = wt*16 .. +15)
  const long long base = (long long)blockIdx.x * (RPB * ROWF);

  // weights -> registers (L2-hot; latency overlaps x staging)
  half4 bf0[4], bf1[4], bf2[4];
  load_bfrag(w0, wt, lane15, laneq, bf0);
  load_bfrag(w1, wt, lane15, laneq, bf1);
  load_bfrag(w2, wt, lane15, laneq, bf2);

  // stage x tile (36 KB contiguous global span -> f16 LDS, [row(n,i)][u])
  stage_seg<1,   0,   0, 16>(lds, x + base, tid);
  stage_seg<3,  64,  16, 48>(lds, x + base, tid);
  stage_seg<5, 256,  64, 80>(lds, x + base, tid);
  __syncthreads();

  // MFMA into registers (36 f32 accs/thread)
  f32x4 acc1[1], acc3[3], acc5[5];
  compute_seg<  0, 1>(lds, lane15, laneq, bf0, acc1);
  compute_seg< 16, 3>(lds, lane15, laneq, bf1, acc3);
  compute_seg< 64, 5>(lds, lane15, laneq, bf2, acc5);
  __syncthreads();                      // x-stage region dead before overwrite

  // half-tile 0: rows 0..7
  scatter_seg<1,   0, 1, 0>(lds, wt, lane15, laneq, acc1);
  scatter_seg<3,  64, 3, 0>(lds, wt, lane15, laneq, acc3);
  scatter_seg<5, 256, 5, 0>(lds, wt, lane15, laneq, acc5);
  __syncthreads();
  copy_half(lds, out + base, tid);
  __syncthreads();

  // half-tile 1: rows 8..15
  scatter_seg<1,   0, 1, 1>(lds, wt, lane15, laneq, acc1);
  scatter_seg<3,  64, 3, 1>(lds, wt, lane15, laneq, acc3);
  scatter_seg<5, 256, 5, 1>(lds, wt, lane15, laneq, acc5);
  __syncthreads();
  copy_half(lds, out + base + HTROWS * ROWF, tid);
}

extern "C" void kernel_launch(void* const* d_in, const int* in_sizes, int n_in,
                              void* d_out, int out_size, void* d_ws, size_t ws_size,
                              hipStream_t stream) {
  const float* x  = (const float*)d_in[0];
  const float* w0 = (const float*)d_in[1];
  const float* w1 = (const float*)d_in[2];
  const float* w2 = (const float*)d_in[3];
  float* out = (float*)d_out;
  linear_irreps<<<NROWS / RPB, 256, 0, stream>>>(x, w0, w1, w2, out);
}

// Round 6
// 249.242 us; speedup vs baseline: 1.8682x; 1.0457x over previous
//
#include <hip/hip_runtime.h>

// irreps Linear: out[n, off_l + w*d + i] = 0.125 * sum_u x[n, off_l + u*d + i] * Wl[u][w]
// N=262144 rows of 576 = [64x(d=1) | 64x(d=3) | 64x(d=5)].
// HBM floor ~906 MB (L3 serves ~half the reads) @ 6.3 TB/s => ~150-190 us. R3 = 248 us.
// R6: producer/consumer wave specialization. 512-thread blocks: waves 0-3 stage
// tile t+1 (global->reg->f16 transposed LDS, R3's stage code) while waves 4-7
// compute tile t (R3's compute+scatter). Read latency hides under compute
// instead of sitting at a barrier drain (R4: reg-prefetch across barriers is
// compiler-defeated; R5: more blocks/CU doesn't help).
// LDS = 2 x 18432 (f16 stage dbuf) + 18432 (8-row out tile) = 55296 -> 2 blocks/CU.

typedef _Float16 half4  __attribute__((ext_vector_type(4)));
typedef float    f32x4  __attribute__((ext_vector_type(4)));

#define NROWS   262144
#define ROWF    576                 // floats per row
#define RPB     16                  // rows per tile
#define TILEF   (RPB * ROWF)        // 9216 floats per tile
#define NTILES  (NROWS / RPB)       // 16384
#define NWG     2048
#define TPW     (NTILES / NWG)      // 8 tiles per WG
#define STG_B   18432               // f16 transposed stage: 144 rows x 128 B
#define HT_B    18432               // out half-tile: 8 x 576 x 4
#define LDS_B   (2 * STG_B + HT_B)  // 55296

// ---- stage one l-segment of x into LDS as f16; LDS rows = (n_local*D + i), cols = u.
// XOR swizzle (row&7)<<4 breaks the 128B-stride same-bank pattern. 256 staging threads.
template<int D, int OFF, int SEGROW, int F4PR>
__device__ __forceinline__ void stage_seg(unsigned char* stg, const float* __restrict__ xrow0, int tid) {
#pragma unroll
  for (int it = 0; it < RPB * F4PR / 256; ++it) {  // 1 / 3 / 5 iters, no tail
    int t = tid + it * 256;
    int row = t / F4PR;                 // const divisor -> magic mul
    int f4  = t - row * F4PR;
    f32x4 v = *(const f32x4*)(xrow0 + (long long)row * ROWF + OFF + f4 * 4);
    int idx = f4 * 4;                   // element index within segment (= u*D + i)
    if (D == 1) {
      int lrow = SEGROW + row;
      int b = (lrow * 128 + idx * 2) ^ ((lrow & 7) << 4);
      half4 h = { (_Float16)v[0], (_Float16)v[1], (_Float16)v[2], (_Float16)v[3] };
      *(half4*)(stg + b) = h;           // 4 consecutive u: one 8B write
    } else {
#pragma unroll
      for (int j = 0; j < 4; ++j) {
        int u = (idx + j) / D;          // const divisor
        int i = (idx + j) - u * D;
        int lrow = SEGROW + row * D + i;
        int b = (lrow * 128 + u * 2) ^ ((lrow & 7) << 4);
        *(_Float16*)(stg + b) = (_Float16)v[j];
      }
    }
  }
}

__device__ __forceinline__ void stage_tile(unsigned char* stg, const float* __restrict__ xs, int tid) {
  stage_seg<1,   0,  0, 16>(stg, xs, tid);
  stage_seg<3,  64, 16, 48>(stg, xs, tid);
  stage_seg<5, 256, 64, 80>(stg, xs, tid);
}

// B-fragments for wt: bf[s][j] = W[u = s*16 + 4*laneq + j][w = wt*16 + lane15]
__device__ __forceinline__ void load_bfrag(const float* __restrict__ W, int wt,
                                           int lane15, int laneq, half4 bf[4]) {
  int w = wt * 16 + lane15;
#pragma unroll
  for (int s = 0; s < 4; ++s) {
    int u0 = s * 16 + laneq * 4;
#pragma unroll
    for (int j = 0; j < 4; ++j)
      bf[s][j] = (_Float16)W[(u0 + j) * 64 + w];   // 16-lane groups read 64B contig
  }
}

// MFMA all m-tiles of one l-segment for this wave's w-tile
template<int SEGROW, int MT>
__device__ __forceinline__ void compute_seg(const unsigned char* stg, int lane15, int laneq,
                                            const half4 bf[4], f32x4 acc[MT]) {
  const int coff = laneq * 8;           // k-chunk byte offset within a row
#pragma unroll
  for (int mt = 0; mt < MT; ++mt) {
    int arow  = SEGROW + mt * 16 + lane15;   // A: m = lane%16, k = s*16 + 4*laneq + j
    int abase = arow * 128;
    int aswz  = (arow & 7) << 4;
    acc[mt] = (f32x4){0.f, 0.f, 0.f, 0.f};
#pragma unroll
    for (int s = 0; s < 4; ++s) {
      half4 a = *(const half4*)(stg + abase + ((s * 32 + coff) ^ aswz));
      acc[mt] = __builtin_amdgcn_mfma_f32_16x16x16f16(a, bf[s], acc[mt], 0, 0, 0);
    }
  }
}

// scatter this phase's acc fragments into the f32 out half-tile in LDS
// (rows n in [PHASE*8, PHASE*8+8) stored at n - PHASE*8, row-major [8][576])
template<int D, int OFF, int MT, int PHASE>
__device__ __forceinline__ void scatter_seg(unsigned char* outl, int wt, int lane15, int laneq,
                                            const f32x4 acc[MT]) {
  const int w = wt * 16 + lane15;
#pragma unroll
  for (int mt = 0; mt < MT; ++mt) {
#pragma unroll
    for (int j = 0; j < 4; ++j) {
      int r = mt * 16 + laneq * 4 + j;  // D-frag: col = lane&15, row = 4*laneq + j
      int n = r / D;                    // const divisor
      int i = r - n * D;
      bool sel = PHASE ? (n >= 8) : (n < 8);
      if (sel)
        *(float*)(outl + (n - PHASE * 8) * (ROWF * 4) + (OFF + w * D + i) * 4)
            = 0.125f * acc[mt][j];
    }
  }
}

// coalesced copy of one 8x576 f32 half-tile to global (1152 float4s, 512 threads)
__device__ __forceinline__ void copy_half(const unsigned char* outl, float* __restrict__ dst, int tid) {
#pragma unroll
  for (int k = 0; k < 2; ++k) {
    int q = tid + k * 512;
    *(f32x4*)(dst + q * 4) = *(const f32x4*)(outl + q * 16);
  }
  if (tid < 128) {
    int q = tid + 1024;
    *(f32x4*)(dst + q * 4) = *(const f32x4*)(outl + q * 16);
  }
}

__global__ __launch_bounds__(512, 2) void linear_irreps(
    const float* __restrict__ x,
    const float* __restrict__ w0, const float* __restrict__ w1, const float* __restrict__ w2,
    float* __restrict__ out) {
  __shared__ __align__(16) unsigned char lds[LDS_B];
  unsigned char* outl = lds + 2 * STG_B;
  const int tid = threadIdx.x;
  const int wave = tid >> 6, lane = tid & 63;
  const int lane15 = lane & 15, laneq = lane >> 4;
  const bool producer = (wave < 4);
  const int wt = wave & 3;              // consumers (waves 4-7): w-tile = wave-4

  // weights -> registers (L2-hot; consumers use them, producers just carry them)
  half4 bf0[4], bf1[4], bf2[4];
  load_bfrag(w0, wt, lane15, laneq, bf0);
  load_bfrag(w1, wt, lane15, laneq, bf1);
  load_bfrag(w2, wt, lane15, laneq, bf2);

  const long long t0 = (long long)blockIdx.x * TPW;

  // prologue: producers stage tile 0 into stg[0]
  if (producer) stage_tile(lds, x + t0 * TILEF, tid);
  __syncthreads();

  for (int k = 0; k < TPW; ++k) {
    const long long tt = t0 + k;
    unsigned char* cur = lds + (k & 1) * STG_B;
    unsigned char* nxt = lds + ((k & 1) ^ 1) * STG_B;
    f32x4 acc1[1], acc3[3], acc5[5];

    if (producer) {
      // stage tile t+1 while consumers compute tile t
      if (k + 1 < TPW) stage_tile(nxt, x + (tt + 1) * TILEF, tid);
    } else {
      compute_seg< 0, 1>(cur, lane15, laneq, bf0, acc1);
      compute_seg<16, 3>(cur, lane15, laneq, bf1, acc3);
      compute_seg<64, 5>(cur, lane15, laneq, bf2, acc5);
      scatter_seg<1,   0, 1, 0>(outl, wt, lane15, laneq, acc1);
      scatter_seg<3,  64, 3, 0>(outl, wt, lane15, laneq, acc3);
      scatter_seg<5, 256, 5, 0>(outl, wt, lane15, laneq, acc5);
    }
    __syncthreads();                    // staging + scatter(0-7) complete

    float* dst = out + tt * TILEF;
    copy_half(outl, dst, tid);          // all 8 waves copy rows 0-7
    __syncthreads();                    // out region free

    if (!producer) {
      scatter_seg<1,   0, 1, 1>(outl, wt, lane15, laneq, acc1);
      scatter_seg<3,  64, 3, 1>(outl, wt, lane15, laneq, acc3);
      scatter_seg<5, 256, 5, 1>(outl, wt, lane15, laneq, acc5);
    }
    __syncthreads();                    // scatter(8-15) complete

    copy_half(outl, dst + 8 * ROWF, tid);
    __syncthreads();                    // out free + cur free for next staging
  }
}

extern "C" void kernel_launch(void* const* d_in, const int* in_sizes, int n_in,
                              void* d_out, int out_size, void* d_ws, size_t ws_size,
                              hipStream_t stream) {
  const float* x  = (const float*)d_in[0];
  const float* w0 = (const float*)d_in[1];
  const float* w1 = (const float*)d_in[2];
  const float* w2 = (const float*)d_in[3];
  float* out = (float*)d_out;
  linear_irreps<<<NWG, 512, 0, stream>>>(x, w0, w1, w2, out);
}